// Round 1
// baseline (712.726 us; speedup 1.0000x reference)
//
#include <hip/hip_runtime.h>
#include <math.h>

// GenModel: 4096 independent SDE particles.
//   z_term -> 64 RK4 steps (drift -f) -> z_init -> 4095 EM steps (drift +f, diff g)
// f: 2->24 tanh ->2 MLP.  g: 2->24 tanh ->1 MLP -> 0.3*sigmoid.
// Mapping: 16 lanes per particle; 24 f-units + 24 g-units split 3 per lane.
// Reductions over the 16-lane group via DPP butterfly (VALU-only, no LDS).
// 65536 threads = 1024 waves = 1 wave per SIMD on MI355X.

#define NPART  4096
#define NSTEPS 4095   // EM steps
#define NH     24

__device__ __forceinline__ float exp2_hw(float x) {
  float r;
  asm("v_exp_f32 %0, %1" : "=v"(r) : "v"(x));   // exp2; gfx9 VALU interlocked
  return r;
}

template<int CTRL>
__device__ __forceinline__ float dpp_add16(float x) {
  int s = __builtin_amdgcn_update_dpp(0, __float_as_int(x), CTRL, 0xF, 0xF, true);
  return x + __int_as_float(s);
}

// sum over each 16-lane row; every lane ends with the (bit-identical) total
__device__ __forceinline__ float rsum16(float x) {
  x = dpp_add16<0xB1>(x);   // quad_perm [1,0,3,2] : xor1
  x = dpp_add16<0x4E>(x);   // quad_perm [2,3,0,1] : xor2
  x = dpp_add16<0x141>(x);  // row_half_mirror     : xor4 (quads uniform by now)
  x = dpp_add16<0x140>(x);  // row_mirror          : xor8
  return x;
}

__device__ __forceinline__ float tanh_hw(float x) {
  // tanh(x) = 1 - 2/(1 + e^{2x});  e^{2x} = 2^{x*2*log2(e)}
  float e = exp2_hw(x * 2.8853900817779268f);
  float r = __builtin_amdgcn_rcpf(1.0f + e);
  return fmaf(-2.0f, r, 1.0f);
}

__global__ void __launch_bounds__(256)
sde_kernel(const float* __restrict__ Wf1, const float* __restrict__ bf1,
           const float* __restrict__ Wf2, const float* __restrict__ bf2,
           const float* __restrict__ Wg1, const float* __restrict__ bg1,
           const float* __restrict__ Wg2, const float* __restrict__ bg2,
           const float* __restrict__ term_loc, const float* __restrict__ lts,
           const float* __restrict__ eps, const float* __restrict__ dW,
           float* __restrict__ out)
{
  const int tid = blockIdx.x * blockDim.x + threadIdx.x;
  const int pid = tid >> 4;          // particle id 0..4095
  const int l   = tid & 15;          // lane within particle group
  const bool lane0 = (l == 0);

  // ---- per-lane unit weights (3 hidden units per lane) ----
  // unit0: f-unit l        unit1: l<8 ? f-unit l+16 : g-unit l+8     unit2: g-unit l
  float u0w0 = Wf1[l], u0w1 = Wf1[NH + l], u0b = bf1[l];
  float u0o0 = Wf2[2*l], u0o1 = Wf2[2*l+1];

  float u1w0, u1w1, u1b, u1o0, u1o1, u1og;
  if (l < 8) {
    int h = l + 16;
    u1w0 = Wf1[h]; u1w1 = Wf1[NH + h]; u1b = bf1[h];
    u1o0 = Wf2[2*h]; u1o1 = Wf2[2*h+1]; u1og = 0.0f;
  } else {
    int h = l + 8;
    u1w0 = Wg1[h]; u1w1 = Wg1[NH + h]; u1b = bg1[h];
    u1o0 = 0.0f; u1o1 = 0.0f; u1og = Wg2[h];
  }
  float u2w0 = Wg1[l], u2w1 = Wg1[NH + l], u2b = bg1[l], u2og = Wg2[l];

  const float bf20 = bf2[0], bf21 = bf2[1], bg20 = bg2[0];

  // ---- issue dW chunk-0 prefetch early; RK4 below hides the latency ----
  const float2* dwp = (const float2*)dW + pid;   // dW[t][pid][:] = dwp[t*NPART]
  float2 bufA[8], bufB[8];
  #pragma unroll
  for (int k = 0; k < 8; ++k) bufA[k] = dwp[(size_t)k * NPART];

  // ---- z_term ----
  const int p = pid & 3;
  const float stdv = expf(lts[p]);
  float z0 = fmaf(stdv, eps[2*pid],   term_loc[2*p]);
  float z1 = fmaf(stdv, eps[2*pid+1], term_loc[2*p+1]);

  // ---- f-only evaluator (units 0 and 1; g-only lanes contribute 0) ----
  auto evalF = [&](float y0, float y1, float& F0, float& F1) {
    float pre0 = fmaf(y0, u0w0, fmaf(y1, u0w1, u0b));
    float pre1 = fmaf(y0, u1w0, fmaf(y1, u1w1, u1b));
    float t0 = tanh_hw(pre0);
    float t1 = tanh_hw(pre1);
    float a0 = fmaf(t1, u1o0, t0 * u0o0);
    float a1 = fmaf(t1, u1o1, t0 * u0o1);
    F0 = rsum16(a0) + bf20;
    F1 = rsum16(a1) + bf21;
  };

  // ---- RK4: dz/ds = -f(z), 64 steps, dt = 1/64 ----
  const float dt = 1.0f / 64.0f;
  #pragma unroll 1
  for (int s = 0; s < 64; ++s) {
    float K10,K11,K20,K21,K30,K31,K40,K41;   // K = f(.), k_ref = -K
    evalF(z0, z1, K10, K11);
    evalF(fmaf(-0.5f*dt, K10, z0), fmaf(-0.5f*dt, K11, z1), K20, K21);
    evalF(fmaf(-0.5f*dt, K20, z0), fmaf(-0.5f*dt, K21, z1), K30, K31);
    evalF(fmaf(-dt, K30, z0), fmaf(-dt, K31, z1), K40, K41);
    z0 -= dt*(1.0f/6.0f) * (K10 + 2.0f*(K20 + K30) + K40);
    z1 -= dt*(1.0f/6.0f) * (K11 + 2.0f*(K21 + K31) + K41);
  }

  // ---- outputs layout ----
  float* zinit = out;
  float* zforw = out + 2*NPART;
  float* zsamp = out + 2*NPART + 2*(size_t)NPART*NPART;

  if (lane0) {
    *(float2*)(zinit + 2*pid) = make_float2(z0, z1);
    *(float2*)(zforw + 2*pid) = make_float2(z0, z1);      // z_forw[0] = z_init
    if (pid == 0) *(float2*)zsamp = make_float2(z0, z1);  // diag t=0
  }

  // ---- EM: z += f(z)*dts + 0.3*sigmoid(gpre)*sqdt*dw ----
  const float dts  = 1.0f / (float)NSTEPS;
  const float sqdt = sqrtf(dts);
  const float gsc  = 0.3f * sqdt;
  const int pid_m1 = pid - 1;
  float s0 = 0.0f, s1 = 0.0f;
  float* zfp = zforw + 2*pid + 2*NPART;   // row t+1, advance 2*NPART floats/step

  auto loadc = [&](float2* buf, int c) {
    #pragma unroll
    for (int k = 0; k < 8; ++k) {
      int tt = c*8 + k; if (tt > NSTEPS-1) tt = NSTEPS-1;
      buf[k] = dwp[(size_t)tt * NPART];
    }
  };

  auto step = [&](float2 dw, int t) {
    float pre0 = fmaf(z0, u0w0, fmaf(z1, u0w1, u0b));
    float pre1 = fmaf(z0, u1w0, fmaf(z1, u1w1, u1b));
    float pre2 = fmaf(z0, u2w0, fmaf(z1, u2w1, u2b));
    float t0 = tanh_hw(pre0);
    float t1 = tanh_hw(pre1);
    float t2 = tanh_hw(pre2);
    float aF0 = fmaf(t1, u1o0, t0 * u0o0);
    float aF1 = fmaf(t1, u1o1, t0 * u0o1);
    float aG  = fmaf(t2, u2og, t1 * u1og);
    aF0 = rsum16(aF0) + bf20;
    aF1 = rsum16(aF1) + bf21;
    aG  = rsum16(aG)  + bg20;
    // 0.3*sigmoid(aG)*sqdt
    float sg = __builtin_amdgcn_rcpf(1.0f + exp2_hw(aG * -1.4426950408889634f));
    float c  = gsc * sg;
    z0 = fmaf(aF0, dts, z0); z0 = fmaf(c, dw.x, z0);
    z1 = fmaf(aF1, dts, z1); z1 = fmaf(c, dw.y, z1);
    if (lane0) *(float2*)zfp = make_float2(z0, z1);
    zfp += 2*NPART;
    if (t == pid_m1) { s0 = z0; s1 = z1; }   // diagonal sample
  };

  // main pipeline: chunks 0..509 full, prefetch one chunk ahead
  #pragma unroll 1
  for (int c = 0; c < 510; c += 2) {
    loadc(bufB, c + 1);
    #pragma unroll
    for (int k = 0; k < 8; ++k) step(bufA[k], c*8 + k);
    loadc(bufA, c + 2);
    #pragma unroll
    for (int k = 0; k < 8; ++k) step(bufB[k], (c+1)*8 + k);
  }
  // epilogue: chunk 510 (full) + chunk 511 (7 steps -> t=4094)
  loadc(bufB, 511);
  #pragma unroll
  for (int k = 0; k < 8; ++k) step(bufA[k], 4080 + k);
  #pragma unroll
  for (int k = 0; k < 7; ++k) step(bufB[k], 4088 + k);

  if (lane0 && pid > 0) *(float2*)(zsamp + 2*pid) = make_float2(s0, s1);
}

extern "C" void kernel_launch(void* const* d_in, const int* in_sizes, int n_in,
                              void* d_out, int out_size, void* d_ws, size_t ws_size,
                              hipStream_t stream) {
  // setup_inputs order: [0]=N, [1]=Wf1, [2]=bf1, [3]=Wf2, [4]=bf2,
  // [5]=Wg1, [6]=bg1, [7]=Wg2, [8]=bg2, [9]=term_loc, [10]=log_term_std,
  // [11]=noise_eps, [12]=dW
  sde_kernel<<<dim3(256), dim3(256), 0, stream>>>(
      (const float*)d_in[1],  (const float*)d_in[2],
      (const float*)d_in[3],  (const float*)d_in[4],
      (const float*)d_in[5],  (const float*)d_in[6],
      (const float*)d_in[7],  (const float*)d_in[8],
      (const float*)d_in[9],  (const float*)d_in[10],
      (const float*)d_in[11], (const float*)d_in[12],
      (float*)d_out);
}